// Round 10
// baseline (65.151 us; speedup 1.0000x reference)
//
#include <hip/hip_runtime.h>

typedef unsigned int u32;
typedef unsigned short u16;
typedef __attribute__((ext_vector_type(8))) _Float16 f16x8;
typedef __attribute__((ext_vector_type(2))) _Float16 f16x2;
typedef __attribute__((ext_vector_type(4))) float f32x4;

namespace {

constexpr int kH = 48, kW = 48, kHW = kH * kW;     // 2304
constexpr int kC = 256;
constexpr int kB = 2;
constexpr int kM = kB * kHW;                        // 4608 GEMM rows
constexpr int kPH = 54, kPW = 56, kPP = kPH * kPW;  // padded kv grid (3024)
constexpr float kInvTemp = 0.17677669529663687f;    // 1/sqrt(32)

constexpr size_t KPAD_U16 = (size_t)16 * kPP * 32;  // 1,548,288 u16 per mat
constexpr size_t QBF_U16 = (size_t)kM * kC;         // 1,179,648 u16
// border zeroing: 720 border pixels/plane x 16 planes x 2 mats x 4 uint4
constexpr int kZeroTasks = 720 * 16 * 2 * 4;        // 92,160
constexpr int kZeroPerBlk = 54;                     // 1728 qkv blocks x 54 >= 92160

__device__ __forceinline__ u32 pack2h(float lo, float hi) {
  return __builtin_bit_cast(u32, __builtin_amdgcn_cvt_pkrtz(lo, hi));
}
__device__ __forceinline__ u16 f2h(float f) {
  return __builtin_bit_cast(u16, (_Float16)f);
}
__device__ __forceinline__ float f4e(const float4 v, int i) {
  return (i == 0) ? v.x : (i == 1) ? v.y : (i == 2) ? v.z : v.w;
}
__device__ __forceinline__ void dot8(float& d, uint4 r, const float* qf) {
  const f16x8 h = __builtin_bit_cast(f16x8, r);
#pragma unroll
  for (int j = 0; j < 8; ++j) d += (float)h[j] * qf[j];
}

// ---------------------------------------------------------------------------
// Fused QKV GEMM, 32x64 tiles -> 1728 blocks (R7-proven, verbatim).
// z=0: q -> f16 [m][256].  z=1/2: k/v -> zero-padded f16 [bh][54*56][32].
// Also zeroes the pad borders (disjoint from interior epilogue writes).
// ---------------------------------------------------------------------------
__global__ __launch_bounds__(256) void gemm_qkv_kernel(
    const float* __restrict__ q, const float* __restrict__ k,
    const float* __restrict__ v, const float* __restrict__ Wq,
    const float* __restrict__ Wk, const float* __restrict__ Wv,
    u16* __restrict__ qbf, u16* __restrict__ kpad, u16* __restrict__ vpad) {
  __shared__ __align__(16) u16 As[32 * 64];
  __shared__ __align__(16) u16 Bs[64 * 64];
  const int t = threadIdx.x;

  // ---- border zeroing (1.5 MB total across the 1728 blocks) ----
  {
    const int bid = (blockIdx.z * 4 + blockIdx.y) * 144 + blockIdx.x;
    const int T = bid * kZeroPerBlk + t;
    if (t < kZeroPerBlk && T < kZeroTasks) {
      const int ch = T & 3, rest = T >> 2;  // rest < 23040
      const int pm = rest / 720, bi = rest - pm * 720;
      int y, x;
      if (bi < 336) {  // full rows 0,1,2,51,52,53
        const int r = bi / 56, c = bi - (bi / 56) * 56;
        y = (r < 3) ? r : 48 + r;
        x = c;
      } else {  // rows 3..50, cols {0,1,2,51..55}
        const int r = (bi - 336) >> 3, c = (bi - 336) & 7;
        y = 3 + r;
        x = (c < 3) ? c : c + 48;
      }
      u16* pb = (pm >= 16) ? vpad : kpad;
      const uint4 zz = {0u, 0u, 0u, 0u};
      *(uint4*)&pb[((size_t)(pm & 15) * kPP + y * kPW + x) * 32 + ch * 8] = zz;
    }
  }

  const int z = blockIdx.z;
  const float* X = (z == 0) ? q : (z == 1) ? k : v;
  const float* Wm = (z == 0) ? Wq : (z == 1) ? Wk : Wv;
  const int m0 = blockIdx.x * 32, n0 = blockIdx.y * 64;
  const int bb = m0 / kHW, p0 = m0 - bb * kHW;  // 2304%32==0: no straddle
  const int l = t & 63, w = t >> 6, wm = w >> 1, wn = w & 1;
  const int mq = t & 7, kp = t >> 3;  // kp in [0,32): c-pair index

  f32x4 acc[2];
#pragma unroll
  for (int nf = 0; nf < 2; ++nf) acc[nf] = (f32x4){0.f, 0.f, 0.f, 0.f};

  for (int kt = 0; kt < 4; ++kt) {
    const int k0 = kt * 64;
    if (kt) __syncthreads();
    // A stage: 2 coalesced c-row float4 reads, 4x2 register transpose,
    // pkrtz pack, 4B swizzled LDS writes. (row stride 128B, swz bits 4-6 ok)
    {
      const float* ab =
          X + ((size_t)(bb * kC + k0 + kp * 2)) * kHW + p0 + mq * 4;
      const float4 r0 = *(const float4*)(ab);
      const float4 r1 = *(const float4*)(ab + kHW);
#pragma unroll
      for (int i = 0; i < 4; ++i) {
        const int ml = mq * 4 + i;
        const u32 pk = pack2h(f4e(r0, i), f4e(r1, i));
        const int bo = (kp * 4) ^ ((ml & 7) << 4);
        *(u32*)&As[ml * 64 + (bo >> 1)] = pk;
      }
    }
    // B stage: fp32 W[o][c] -> f16, same swizzle (64 rows x 16 float4)
#pragma unroll
    for (int j = 0; j < 4; ++j) {
      const int task2 = t + j * 256;
      const int rr = task2 >> 4, f4i = task2 & 15;
      const float4 val =
          *(const float4*)&Wm[(size_t)(n0 + rr) * kC + k0 + f4i * 4];
      uint2 pk;
      pk.x = pack2h(val.x, val.y);
      pk.y = pack2h(val.z, val.w);
      const int bo = (f4i * 8) ^ ((rr & 7) << 4);
      *(uint2*)&Bs[rr * 64 + (bo >> 1)] = pk;
    }
    __syncthreads();
#pragma unroll
    for (int ks = 0; ks < 2; ++ks) {
      const int bo = ks * 64 + ((l >> 4) << 4);
      const int rowa = wm * 16 + (l & 15);
      const f16x8 a =
          *(const f16x8*)&As[rowa * 64 + ((bo ^ ((rowa & 7) << 4)) >> 1)];
      f16x8 bfr[2];
#pragma unroll
      for (int nf = 0; nf < 2; ++nf) {
        const int row = wn * 32 + nf * 16 + (l & 15);
        bfr[nf] =
            *(const f16x8*)&Bs[row * 64 + ((bo ^ ((row & 7) << 4)) >> 1)];
      }
#pragma unroll
      for (int nf = 0; nf < 2; ++nf)
        acc[nf] = __builtin_amdgcn_mfma_f32_16x16x32_f16(a, bfr[nf], acc[nf],
                                                         0, 0, 0);
    }
  }

  u16* pd = (z == 1) ? kpad : vpad;
#pragma unroll
  for (int nf = 0; nf < 2; ++nf)
#pragma unroll
    for (int i = 0; i < 4; ++i) {
      const int m = m0 + wm * 16 + ((l >> 4) << 2) + i;
      const int o = n0 + wn * 32 + nf * 16 + (l & 15);
      const float val = acc[nf][i];
      if (z == 0) {
        qbf[(size_t)m * kC + o] = f2h(val);
      } else {
        const int p = m - bb * kHW;
        const int y = p / kW, x = p - (p / kW) * kW;
        pd[((size_t)(bb * 8 + (o >> 5)) * kPP + (y + 3) * kPW + (x + 3)) * 32 +
           (o & 31)] = f2h(val);
      }
    }
}

// ---------------------------------------------------------------------------
// Fused attention + FC. Block = 256 thr = one (b, 4x4-pixel tile).
// Loop h=0..7: stage 10x10 halo of k,v (head h) -> per-pixel 16-lane attn
// (neighbor-split QK, LDS softmax weights, channel-split PV) -> att_s in LDS.
// Then FC GEMM M=256(o) x N=16(px) x K=256 from LDS + residual.
// FIX vs R9: FC As rows are 64 B, so the XOR swizzle must be 2 bits
// ((row&3)<<4); the former (row&7)<<4 spanned 128 B and collided rows
// r and r+4 (bit 6 escaped the row) -> corrupted Wfc tile, absmax 0.607.
// ---------------------------------------------------------------------------
__global__ __launch_bounds__(256) void attnfc_kernel(
    const u16* __restrict__ qbf, const u16* __restrict__ kpad,
    const u16* __restrict__ vpad, const float* __restrict__ Wfc,
    const float* __restrict__ Res, float* __restrict__ Out) {
  __shared__ __align__(16) union SharedU {
    struct {
      u16 kh[100 * 40];  // 10x10 halo, row stride 40 u16
      u16 vh[100 * 40];
    } a;                  // 16,000 B (attn)
    u16 As[256 * 32];     // 16,384 B (FC Wfc tile, 64 B rows)
  } sh;
  __shared__ __align__(16) u16 att_s[16 * 256];  // 8 KB, 512 B rows
  __shared__ float s_lds[16][52];                // softmax weights per px

  const int t = threadIdx.x;
  const int tile = blockIdx.x, bb = blockIdx.y;
  const int tyi = tile / 12, txi = tile - tyi * 12;
  const int y0 = tyi * 4, x0 = txi * 4;
  const int pxid = t >> 4, ng = t & 15;  // 16 px x 16 lanes
  const int py = pxid >> 2, px_ = pxid & 3;
  const int gp = (y0 + py) * kW + (x0 + px_);
  const int hpbase = py * 10 + px_;

#pragma unroll 1
  for (int hd = 0; hd < 8; ++hd) {
    __syncthreads();  // previous head's LDS readers done
    // stage halo: 100 px x 4 uint4 x {k,v} = 800 tasks
    const size_t plane = (size_t)(bb * 8 + hd) * kPP;
    for (int task = t; task < 800; task += 256) {
      const int mat = task >= 400;
      const int rem = task - mat * 400;
      const int hp = rem >> 2, ch = rem & 3;
      const int hy = hp / 10, hx = hp - hy * 10;
      const size_t src = (plane + (y0 + hy) * kPW + (x0 + hx)) * 32 + ch * 8;
      const uint4 val = *(const uint4*)&(mat ? vpad : kpad)[src];
      u16* dst = mat ? sh.a.vh : sh.a.kh;
      *(uint4*)&dst[hp * 40 + ch * 8] = val;
    }
    // q for this pixel/head (redundant across 16 lanes; L1-hit)
    const size_t qb = ((size_t)(bb * kHW + gp)) * kC + hd * 32;
    float qf[32];
#pragma unroll
    for (int c8 = 0; c8 < 4; ++c8) {
      const uint4 qq = *(const uint4*)&qbf[qb + c8 * 8];
      const f16x8 hh = __builtin_bit_cast(f16x8, qq);
#pragma unroll
      for (int j = 0; j < 8; ++j) qf[c8 * 8 + j] = (float)hh[j];
    }
    __syncthreads();  // halo staged

    // QK: neighbor-split, n = nn*16 + ng
    float sv[4];
    float pm = -1e30f;
#pragma unroll
    for (int nn = 0; nn < 4; ++nn) {
      const int n = nn * 16 + ng;
      float sc = -1e30f;
      if (n < 49) {
        const int ky = (n * 147) >> 10, kx = n - ky * 7;  // n/7, n%7
        const int hp = hpbase + ky * 10 + kx;
        const u16* kr = &sh.a.kh[hp * 40];
        float d = 0.f;
        dot8(d, *(const uint4*)&kr[0], qf + 0);
        dot8(d, *(const uint4*)&kr[8], qf + 8);
        dot8(d, *(const uint4*)&kr[16], qf + 16);
        dot8(d, *(const uint4*)&kr[24], qf + 24);
        sc = d * kInvTemp;
      }
      sv[nn] = sc;
      pm = fmaxf(pm, sc);
    }
    pm = fmaxf(pm, __shfl_xor(pm, 1));
    pm = fmaxf(pm, __shfl_xor(pm, 2));
    pm = fmaxf(pm, __shfl_xor(pm, 4));
    pm = fmaxf(pm, __shfl_xor(pm, 8));
    float zs = 0.f;
#pragma unroll
    for (int nn = 0; nn < 4; ++nn) {
      const int n = nn * 16 + ng;
      const float e = __expf(sv[nn] - pm);  // invalid n: exp(-huge) = 0
      zs += e;
      if (n < 49) s_lds[pxid][n] = e;  // same-wave producer/consumer
    }
    zs += __shfl_xor(zs, 1);
    zs += __shfl_xor(zs, 2);
    zs += __shfl_xor(zs, 4);
    zs += __shfl_xor(zs, 8);
    const float rinv = 1.0f / zs;

    // PV: channel-split — lane ng owns channels {2ng, 2ng+1}; no shuffles.
    float o0 = 0.f, o1 = 0.f;
#pragma unroll
    for (int n = 0; n < 49; ++n) {
      const int ky = n / 7, kx = n % 7;  // compile-time
      const int hp = hpbase + ky * 10 + kx;
      const float wgt = s_lds[pxid][n];  // 16-lane broadcast
      const u32 vv = *(const u32*)&sh.a.vh[hp * 40 + ng * 2];
      const f16x2 v2 = __builtin_bit_cast(f16x2, vv);
      o0 += wgt * (float)v2[0];
      o1 += wgt * (float)v2[1];
    }
    const u32 pk = pack2h(o0 * rinv, o1 * rinv);
    *(u32*)((char*)att_s + pxid * 512 +
            ((hd * 64 + ng * 4) ^ ((pxid & 7) << 4))) = pk;
  }

  // ---- FC GEMM: out[o][px] = sum_c Wfc[o][c] * att_s[px][c] + Res ----
  __syncthreads();  // att_s complete; halo region dead (As overlays it)
  const int l = t & 63, w = t >> 6;
  const int kq = l >> 4, pxi = l & 15;
  f32x4 acc[4];
#pragma unroll
  for (int mf = 0; mf < 4; ++mf) acc[mf] = (f32x4){0.f, 0.f, 0.f, 0.f};

  for (int ks = 0; ks < 8; ++ks) {
    if (ks) __syncthreads();
    {  // stage As: 256 o-rows x 32 c of Wfc (fp32 -> f16, 2-bit swizzle)
      const float* wr = &Wfc[(size_t)t * kC + ks * 32];
#pragma unroll
      for (int c4 = 0; c4 < 4; ++c4) {
        const float4 va = *(const float4*)(wr + c4 * 8);
        const float4 vb = *(const float4*)(wr + c4 * 8 + 4);
        uint4 pk4;
        pk4.x = pack2h(va.x, va.y);
        pk4.y = pack2h(va.z, va.w);
        pk4.z = pack2h(vb.x, vb.y);
        pk4.w = pack2h(vb.z, vb.w);
        *(uint4*)((char*)sh.As + t * 64 + ((c4 * 16) ^ ((t & 3) << 4))) = pk4;
      }
    }
    __syncthreads();
    const f16x8 bfr = *(const f16x8*)((const char*)att_s + pxi * 512 +
                                      ((ks * 64 + kq * 16) ^ ((pxi & 7) << 4)));
#pragma unroll
    for (int mf = 0; mf < 4; ++mf) {
      const int rowa = w * 64 + mf * 16 + pxi;
      const f16x8 a = *(const f16x8*)(
          (const char*)sh.As + rowa * 64 + ((kq * 16) ^ ((rowa & 3) << 4)));
      acc[mf] =
          __builtin_amdgcn_mfma_f32_16x16x32_f16(a, bfr, acc[mf], 0, 0, 0);
    }
  }
#pragma unroll
  for (int mf = 0; mf < 4; ++mf)
#pragma unroll
    for (int i = 0; i < 4; ++i) {
      const int o = w * 64 + mf * 16 + kq * 4 + i;
      const int py2 = pxi >> 2, pxx = pxi & 3;
      const int p = (y0 + py2) * kW + (x0 + pxx);
      const size_t addr = ((size_t)(bb * kC + o)) * kHW + p;
      Out[addr] = acc[mf][i] + Res[addr];
    }
}

}  // namespace

extern "C" void kernel_launch(void* const* d_in, const int* in_sizes, int n_in,
                              void* d_out, int out_size, void* d_ws,
                              size_t ws_size, hipStream_t stream) {
  const float* q = (const float*)d_in[0];
  const float* k = (const float*)d_in[1];
  const float* v = (const float*)d_in[2];
  const float* Wq = (const float*)d_in[3];
  const float* Wk = (const float*)d_in[4];
  const float* Wv = (const float*)d_in[5];
  const float* Wfc = (const float*)d_in[6];
  float* out = (float*)d_out;

  u16* ws16 = (u16*)d_ws;
  u16* kpad = ws16;
  u16* vpad = ws16 + KPAD_U16;
  u16* qbf = ws16 + 2 * KPAD_U16;

  gemm_qkv_kernel<<<dim3(kM / 32, kC / 64, 3), 256, 0, stream>>>(
      q, k, v, Wq, Wk, Wv, qbf, kpad, vpad);

  // 144 spatial tiles (4x4 px) x 2 batch = 288 blocks; attn + FC fused.
  attnfc_kernel<<<dim3(144, kB), 256, 0, stream>>>(qbf, kpad, vpad, Wfc, q,
                                                   out);
}

// Round 11
// 53.599 us; speedup vs baseline: 1.2155x; 1.2155x over previous
//
#include <hip/hip_runtime.h>

typedef unsigned int u32;
typedef unsigned short u16;
typedef __attribute__((ext_vector_type(8))) _Float16 f16x8;
typedef __attribute__((ext_vector_type(2))) _Float16 f16x2;
typedef __attribute__((ext_vector_type(4))) float f32x4;

namespace {

constexpr int kH = 48, kW = 48, kHW = kH * kW;     // 2304
constexpr int kC = 256;
constexpr int kB = 2;
constexpr int kM = kB * kHW;                        // 4608 GEMM rows
constexpr int kPH = 54, kPW = 56, kPP = kPH * kPW;  // padded kv grid (3024)
constexpr float kInvTemp = 0.17677669529663687f;    // 1/sqrt(32)

constexpr size_t KPAD_U16 = (size_t)16 * kPP * 32;  // 1,548,288 u16 per mat
constexpr size_t QBF_U16 = (size_t)kM * kC;         // 1,179,648 u16
// border zeroing: 720 border pixels/plane x 16 planes x 2 mats x 4 uint4
constexpr int kZeroTasks = 720 * 16 * 2 * 4;        // 92,160
constexpr int kZeroPerBlk = 54;                     // 1728 qkv blocks x 54 >= 92160

// halo LDS layout: [100 px-rows] x [8 hd x 40 u16] (stride 336 u16 = 672 B:
// px spreads banks by 8, hd by 20 -> conflict-light reads)
constexpr int kRowStr = 336;

__device__ __forceinline__ u32 pack2h(float lo, float hi) {
  return __builtin_bit_cast(u32, __builtin_amdgcn_cvt_pkrtz(lo, hi));
}
__device__ __forceinline__ u16 f2h(float f) {
  return __builtin_bit_cast(u16, (_Float16)f);
}
__device__ __forceinline__ float f4e(const float4 v, int i) {
  return (i == 0) ? v.x : (i == 1) ? v.y : (i == 2) ? v.z : v.w;
}
__device__ __forceinline__ void dot8(float& d, uint4 r, const float* qf) {
  const f16x8 h = __builtin_bit_cast(f16x8, r);
#pragma unroll
  for (int j = 0; j < 8; ++j) d += (float)h[j] * qf[j];
}
__device__ __forceinline__ void pv8(float* of, uint4 r, float e) {
  const f16x8 h = __builtin_bit_cast(f16x8, r);
#pragma unroll
  for (int j = 0; j < 8; ++j) of[j] += e * (float)h[j];
}

// ---------------------------------------------------------------------------
// Fused QKV GEMM, 32x64 tiles -> 1728 blocks (R7-proven, verbatim).
// ---------------------------------------------------------------------------
__global__ __launch_bounds__(256) void gemm_qkv_kernel(
    const float* __restrict__ q, const float* __restrict__ k,
    const float* __restrict__ v, const float* __restrict__ Wq,
    const float* __restrict__ Wk, const float* __restrict__ Wv,
    u16* __restrict__ qbf, u16* __restrict__ kpad, u16* __restrict__ vpad) {
  __shared__ __align__(16) u16 As[32 * 64];
  __shared__ __align__(16) u16 Bs[64 * 64];
  const int t = threadIdx.x;

  // ---- border zeroing (1.5 MB total across the 1728 blocks) ----
  {
    const int bid = (blockIdx.z * 4 + blockIdx.y) * 144 + blockIdx.x;
    const int T = bid * kZeroPerBlk + t;
    if (t < kZeroPerBlk && T < kZeroTasks) {
      const int ch = T & 3, rest = T >> 2;  // rest < 23040
      const int pm = rest / 720, bi = rest - pm * 720;
      int y, x;
      if (bi < 336) {  // full rows 0,1,2,51,52,53
        const int r = bi / 56, c = bi - (bi / 56) * 56;
        y = (r < 3) ? r : 48 + r;
        x = c;
      } else {  // rows 3..50, cols {0,1,2,51..55}
        const int r = (bi - 336) >> 3, c = (bi - 336) & 7;
        y = 3 + r;
        x = (c < 3) ? c : c + 48;
      }
      u16* pb = (pm >= 16) ? vpad : kpad;
      const uint4 zz = {0u, 0u, 0u, 0u};
      *(uint4*)&pb[((size_t)(pm & 15) * kPP + y * kPW + x) * 32 + ch * 8] = zz;
    }
  }

  const int z = blockIdx.z;
  const float* X = (z == 0) ? q : (z == 1) ? k : v;
  const float* Wm = (z == 0) ? Wq : (z == 1) ? Wk : Wv;
  const int m0 = blockIdx.x * 32, n0 = blockIdx.y * 64;
  const int bb = m0 / kHW, p0 = m0 - bb * kHW;  // 2304%32==0: no straddle
  const int l = t & 63, w = t >> 6, wm = w >> 1, wn = w & 1;
  const int mq = t & 7, kp = t >> 3;  // kp in [0,32): c-pair index

  f32x4 acc[2];
#pragma unroll
  for (int nf = 0; nf < 2; ++nf) acc[nf] = (f32x4){0.f, 0.f, 0.f, 0.f};

  for (int kt = 0; kt < 4; ++kt) {
    const int k0 = kt * 64;
    if (kt) __syncthreads();
    {
      const float* ab =
          X + ((size_t)(bb * kC + k0 + kp * 2)) * kHW + p0 + mq * 4;
      const float4 r0 = *(const float4*)(ab);
      const float4 r1 = *(const float4*)(ab + kHW);
#pragma unroll
      for (int i = 0; i < 4; ++i) {
        const int ml = mq * 4 + i;
        const u32 pk = pack2h(f4e(r0, i), f4e(r1, i));
        const int bo = (kp * 4) ^ ((ml & 7) << 4);
        *(u32*)&As[ml * 64 + (bo >> 1)] = pk;
      }
    }
#pragma unroll
    for (int j = 0; j < 4; ++j) {
      const int task2 = t + j * 256;
      const int rr = task2 >> 4, f4i = task2 & 15;
      const float4 val =
          *(const float4*)&Wm[(size_t)(n0 + rr) * kC + k0 + f4i * 4];
      uint2 pk;
      pk.x = pack2h(val.x, val.y);
      pk.y = pack2h(val.z, val.w);
      const int bo = (f4i * 8) ^ ((rr & 7) << 4);
      *(uint2*)&Bs[rr * 64 + (bo >> 1)] = pk;
    }
    __syncthreads();
#pragma unroll
    for (int ks = 0; ks < 2; ++ks) {
      const int bo = ks * 64 + ((l >> 4) << 4);
      const int rowa = wm * 16 + (l & 15);
      const f16x8 a =
          *(const f16x8*)&As[rowa * 64 + ((bo ^ ((rowa & 7) << 4)) >> 1)];
      f16x8 bfr[2];
#pragma unroll
      for (int nf = 0; nf < 2; ++nf) {
        const int row = wn * 32 + nf * 16 + (l & 15);
        bfr[nf] =
            *(const f16x8*)&Bs[row * 64 + ((bo ^ ((row & 7) << 4)) >> 1)];
      }
#pragma unroll
      for (int nf = 0; nf < 2; ++nf)
        acc[nf] = __builtin_amdgcn_mfma_f32_16x16x32_f16(a, bfr[nf], acc[nf],
                                                         0, 0, 0);
    }
  }

  u16* pd = (z == 1) ? kpad : vpad;
#pragma unroll
  for (int nf = 0; nf < 2; ++nf)
#pragma unroll
    for (int i = 0; i < 4; ++i) {
      const int m = m0 + wm * 16 + ((l >> 4) << 2) + i;
      const int o = n0 + wn * 32 + nf * 16 + (l & 15);
      const float val = acc[nf][i];
      if (z == 0) {
        qbf[(size_t)m * kC + o] = f2h(val);
      } else {
        const int p = m - bb * kHW;
        const int y = p / kW, x = p - (p / kW) * kW;
        pd[((size_t)(bb * 8 + (o >> 5)) * kPP + (y + 3) * kPW + (x + 3)) * 32 +
           (o & 31)] = f2h(val);
      }
    }
}

// ---------------------------------------------------------------------------
// Fused attention + FC, v2: all 8 heads in parallel across threads.
// Block = 256 thr = (16 px) x (8 hd) x (2 ch-halves). Serial chain is just
// {stage k(all hd) -> QK -> stage v -> PV -> FC}: ~12 syncs vs v1's ~32,
// no 8-iteration head loop. Softmax fully in-register (lane pair holds all
// 49 scores). FC stage identical to R10 (proven).
// ---------------------------------------------------------------------------
__global__ __launch_bounds__(256) void attnfc_kernel(
    const u16* __restrict__ qbf, const u16* __restrict__ kpad,
    const u16* __restrict__ vpad, const float* __restrict__ Wfc,
    const float* __restrict__ Res, float* __restrict__ Out) {
  __shared__ __align__(16) union SharedU {
    u16 kv[100 * kRowStr];  // 67.2 KB: 10x10 halo, all heads (k then v)
    u16 As[256 * 32];       // 16 KB: FC Wfc tile (64 B rows)
  } sh;
  __shared__ __align__(16) u16 att_s[16 * 256];  // 8 KB, 512 B rows

  const int t = threadIdx.x;
  const int tile = blockIdx.x, bb = blockIdx.y;
  const int tyi = tile / 12, txi = tile - tyi * 12;
  const int y0 = tyi * 4, x0 = txi * 4;
  const int px = t >> 4;        // 0..15
  const int hd = (t >> 1) & 7;  // 0..7
  const int sub = t & 1;        // 0..1 (channel half)
  const int py = px >> 2, pxx = px & 3;
  const int gp = (y0 + py) * kW + (x0 + pxx);
  const int hpbase = py * 10 + pxx;
  const size_t planeb = (size_t)bb * 8;

  // ---- stage k halo, all heads: 100 px x 8 hd x 4 chunks = 3200 uint4 ----
#pragma unroll
  for (int it = 0; it < 13; ++it) {
    const int task = t + it * 256;
    if (task < 3200) {
      const int hp = task >> 5, rem = task & 31;
      const int h2 = rem >> 2, c8 = rem & 3;
      const int hy = hp / 10, hx = hp - hy * 10;
      const size_t src =
          ((planeb + h2) * kPP + (y0 + hy) * kPW + (x0 + hx)) * 32 + c8 * 8;
      *(uint4*)&sh.kv[hp * kRowStr + h2 * 40 + c8 * 8] =
          *(const uint4*)&kpad[src];
    }
  }
  // q: this lane's 16 channels
  float qf[16];
  {
    const size_t qb = ((size_t)(bb * kHW + gp)) * kC + hd * 32 + sub * 16;
    const uint4 a0 = *(const uint4*)&qbf[qb];
    const uint4 a1 = *(const uint4*)&qbf[qb + 8];
    const f16x8 h0 = __builtin_bit_cast(f16x8, a0);
    const f16x8 h1 = __builtin_bit_cast(f16x8, a1);
#pragma unroll
    for (int j = 0; j < 8; ++j) {
      qf[j] = (float)h0[j];
      qf[8 + j] = (float)h1[j];
    }
  }
  __syncthreads();  // k staged

  // ---- QK: 49 neighbors x 16 ch, pair-combine via shfl_xor(1) ----
  float sc[49];
#pragma unroll
  for (int n = 0; n < 49; ++n) {
    const int ky = n / 7, kx = n % 7;  // compile-time
    const u16* kr =
        &sh.kv[(hpbase + ky * 10 + kx) * kRowStr + hd * 40 + sub * 16];
    float d = 0.f;
    dot8(d, *(const uint4*)&kr[0], qf);
    dot8(d, *(const uint4*)&kr[8], qf + 8);
    d += __shfl_xor(d, 1);  // both lanes now hold the full dot
    sc[n] = d * kInvTemp;
  }
  // in-register softmax (identical on both lanes of the pair)
  float pm = sc[0];
#pragma unroll
  for (int n = 1; n < 49; ++n) pm = fmaxf(pm, sc[n]);
  float zs = 0.f;
#pragma unroll
  for (int n = 0; n < 49; ++n) {
    sc[n] = __expf(sc[n] - pm);
    zs += sc[n];
  }
  const float rinv = 1.0f / zs;

  // ---- stage v halo (overwrite k) ----
  __syncthreads();  // QK reads done
#pragma unroll
  for (int it = 0; it < 13; ++it) {
    const int task = t + it * 256;
    if (task < 3200) {
      const int hp = task >> 5, rem = task & 31;
      const int h2 = rem >> 2, c8 = rem & 3;
      const int hy = hp / 10, hx = hp - hy * 10;
      const size_t src =
          ((planeb + h2) * kPP + (y0 + hy) * kPW + (x0 + hx)) * 32 + c8 * 8;
      *(uint4*)&sh.kv[hp * kRowStr + h2 * 40 + c8 * 8] =
          *(const uint4*)&vpad[src];
    }
  }
  __syncthreads();  // v staged

  // ---- PV: 49 neighbors x this lane's 16 channels ----
  float of[16];
#pragma unroll
  for (int j = 0; j < 16; ++j) of[j] = 0.f;
#pragma unroll
  for (int n = 0; n < 49; ++n) {
    const int ky = n / 7, kx = n % 7;
    const u16* vr =
        &sh.kv[(hpbase + ky * 10 + kx) * kRowStr + hd * 40 + sub * 16];
    const float e = sc[n];
    pv8(of, *(const uint4*)&vr[0], e);
    pv8(of + 8, *(const uint4*)&vr[8], e);
  }
  // write att_s[px][hd*32 + sub*16 .. +16] (swizzle matches FC reader)
  {
    uint4 A, Bv;
    A.x = pack2h(of[0] * rinv, of[1] * rinv);
    A.y = pack2h(of[2] * rinv, of[3] * rinv);
    A.z = pack2h(of[4] * rinv, of[5] * rinv);
    A.w = pack2h(of[6] * rinv, of[7] * rinv);
    Bv.x = pack2h(of[8] * rinv, of[9] * rinv);
    Bv.y = pack2h(of[10] * rinv, of[11] * rinv);
    Bv.z = pack2h(of[12] * rinv, of[13] * rinv);
    Bv.w = pack2h(of[14] * rinv, of[15] * rinv);
    char* p = (char*)att_s + px * 512;
    const int base = hd * 64 + sub * 32;
    const int swz = (px & 7) << 4;
    *(uint4*)(p + (base ^ swz)) = A;
    *(uint4*)(p + ((base + 16) ^ swz)) = Bv;
  }

  // ---- FC GEMM: out[o][px] = sum_c Wfc[o][c] * att_s[px][c] + Res ----
  __syncthreads();  // att_s complete; kv dead (As overlays it)
  const int l = t & 63, w = t >> 6;
  const int kq = l >> 4, pxi = l & 15;
  f32x4 acc[4];
#pragma unroll
  for (int mf = 0; mf < 4; ++mf) acc[mf] = (f32x4){0.f, 0.f, 0.f, 0.f};

  for (int ks = 0; ks < 8; ++ks) {
    if (ks) __syncthreads();
    {  // stage As: 256 o-rows x 32 c of Wfc (fp32 -> f16, 2-bit swizzle)
      const float* wr = &Wfc[(size_t)t * kC + ks * 32];
#pragma unroll
      for (int c4 = 0; c4 < 4; ++c4) {
        const float4 va = *(const float4*)(wr + c4 * 8);
        const float4 vb = *(const float4*)(wr + c4 * 8 + 4);
        uint4 pk4;
        pk4.x = pack2h(va.x, va.y);
        pk4.y = pack2h(va.z, va.w);
        pk4.z = pack2h(vb.x, vb.y);
        pk4.w = pack2h(vb.z, vb.w);
        *(uint4*)((char*)sh.As + t * 64 + ((c4 * 16) ^ ((t & 3) << 4))) = pk4;
      }
    }
    __syncthreads();
    const f16x8 bfr = *(const f16x8*)((const char*)att_s + pxi * 512 +
                                      ((ks * 64 + kq * 16) ^ ((pxi & 7) << 4)));
#pragma unroll
    for (int mf = 0; mf < 4; ++mf) {
      const int rowa = w * 64 + mf * 16 + pxi;
      const f16x8 a = *(const f16x8*)(
          (const char*)sh.As + rowa * 64 + ((kq * 16) ^ ((rowa & 3) << 4)));
      acc[mf] =
          __builtin_amdgcn_mfma_f32_16x16x32_f16(a, bfr, acc[mf], 0, 0, 0);
    }
  }
#pragma unroll
  for (int mf = 0; mf < 4; ++mf)
#pragma unroll
    for (int i = 0; i < 4; ++i) {
      const int o = w * 64 + mf * 16 + kq * 4 + i;
      const int py2 = pxi >> 2, pxx2 = pxi & 3;
      const int p = (y0 + py2) * kW + (x0 + pxx2);
      const size_t addr = ((size_t)(bb * kC + o)) * kHW + p;
      Out[addr] = acc[mf][i] + Res[addr];
    }
}

}  // namespace

extern "C" void kernel_launch(void* const* d_in, const int* in_sizes, int n_in,
                              void* d_out, int out_size, void* d_ws,
                              size_t ws_size, hipStream_t stream) {
  const float* q = (const float*)d_in[0];
  const float* k = (const float*)d_in[1];
  const float* v = (const float*)d_in[2];
  const float* Wq = (const float*)d_in[3];
  const float* Wk = (const float*)d_in[4];
  const float* Wv = (const float*)d_in[5];
  const float* Wfc = (const float*)d_in[6];
  float* out = (float*)d_out;

  u16* ws16 = (u16*)d_ws;
  u16* kpad = ws16;
  u16* vpad = ws16 + KPAD_U16;
  u16* qbf = ws16 + 2 * KPAD_U16;

  gemm_qkv_kernel<<<dim3(kM / 32, kC / 64, 3), 256, 0, stream>>>(
      q, k, v, Wq, Wk, Wv, qbf, kpad, vpad);

  // 144 spatial tiles (4x4 px) x 2 batch = 288 blocks; attn + FC fused.
  attnfc_kernel<<<dim3(144, kB), 256, 0, stream>>>(qbf, kpad, vpad, Wfc, q,
                                                   out);
}